// Round 6
// baseline (215.105 us; speedup 1.0000x reference)
//
#include <hip/hip_runtime.h>

// ---------------------------------------------------------------------------
// SelfAttention: B=4, N=4096 tokens/batch, C=512, DQK=64
// out = gamma * softmax((X Wf)(X Wg)^T) (X Wh) + X
// Round 6: single fused projection kernel (x read once -> bf16 frags in regs,
// f/g/v tiles from same frags, sigma-interleaved Vt store), attention l-sum
// via ones-column MFMA (no VALU adds, no epilogue shuffles).
// ---------------------------------------------------------------------------

typedef __bf16 bf16x8 __attribute__((ext_vector_type(8)));
typedef __bf16 bf16x2 __attribute__((ext_vector_type(2)));
typedef float f32x4 __attribute__((ext_vector_type(4)));
typedef unsigned int u32x4 __attribute__((ext_vector_type(4)));
typedef unsigned int u32;

#define L2E 1.4426950408889634f

__device__ __forceinline__ unsigned short f2bf(float f) {
    unsigned int u = __builtin_bit_cast(unsigned int, f);
    u += 0x7fffu + ((u >> 16) & 1u);   // RNE
    return (unsigned short)(u >> 16);
}
__device__ __forceinline__ u32 cvtpk(float a, float b) {
    bf16x2 t; t[0] = (__bf16)a; t[1] = (__bf16)b;   // -> v_cvt_pk_bf16_f32
    return __builtin_bit_cast(u32, t);
}
__device__ __forceinline__ bf16x8 ld8(const void* p) {
    u32x4 u = *reinterpret_cast<const u32x4*>(p);
    return __builtin_bit_cast(bf16x8, u);
}
// two float4 loads + cvt_pk -> bf16x8 fragment
__device__ __forceinline__ bf16x8 ldx(const float* p) {
    float4 a = *reinterpret_cast<const float4*>(p);
    float4 b = *reinterpret_cast<const float4*>(p + 4);
    u32x4 r;
    r.x = cvtpk(a.x, a.y); r.y = cvtpk(a.z, a.w);
    r.z = cvtpk(b.x, b.y); r.w = cvtpk(b.z, b.w);
    return __builtin_bit_cast(bf16x8, r);
}
__device__ __forceinline__ f32x4 mfma16(bf16x8 a, bf16x8 b, f32x4 c) {
    return __builtin_amdgcn_mfma_f32_16x16x32_bf16(a, b, c, 0, 0, 0);
}
__device__ __forceinline__ void gl2lds16(const void* g, void* l) {
    __builtin_amdgcn_global_load_lds(
        (const __attribute__((address_space(1))) u32*)g,
        (__attribute__((address_space(3))) u32*)l, 16, 0, 0);
}

// --------------------------- prep kernel -----------------------------------

// all three weights -> transposed bf16, one launch
__global__ __launch_bounds__(256) void cvt_w_all(const float* __restrict__ kf,
                                                 const float* __restrict__ kg,
                                                 const float* __restrict__ kh,
                                                 unsigned short* __restrict__ wfg,
                                                 unsigned short* __restrict__ wth) {
    int idx = blockIdx.x * 256 + threadIdx.x;
    if (idx < 32768) {
        int n = idx >> 9, k = idx & 511;
        wfg[idx] = f2bf(kf[k * 64 + n]);
    } else if (idx < 65536) {
        int t = idx - 32768;
        int n = t >> 9, k = t & 511;
        wfg[idx] = f2bf(kg[k * 64 + n]);
    } else {
        int t = idx - 65536;
        int n = t >> 9, k = t & 511;
        wth[t] = f2bf(kh[k * 512 + n]);
    }
}

// --------------------- fused projection kernel -----------------------------
// Grid dim3(256, 2): [64-row m-stripe, column-group]. x read once per block
// into 16 bf16x8 register fragments; 5 output tiles of 64 cols per group.
//   group 0: FG tiles {0,1} -> FGb; V tiles n0 = {0,64,128}
//   group 1: V tiles n0 = {192,256,320,384,448}
// V tiles stored transposed (Vt[b][c][n]) with quartet sigma-interleave.
__global__ __launch_bounds__(256, 2) void proj_k(const float* __restrict__ x,
                                                 const unsigned short* __restrict__ wfg,
                                                 const unsigned short* __restrict__ wth,
                                                 unsigned short* __restrict__ fgb,
                                                 unsigned short* __restrict__ vt) {
    __shared__ unsigned short Tl[64][72];
    int m0 = blockIdx.x * 64;
    int grp = blockIdx.y;
    int tid = threadIdx.x;
    int w = tid >> 6, l = tid & 63, g = l >> 4, i = l & 15;

    const float* xrow = x + (size_t)(m0 + 16 * w + i) * 512 + g * 8;
    bf16x8 af[16];
#pragma unroll
    for (int k = 0; k < 16; k++) af[k] = ldx(xrow + 32 * k);

    int b = m0 >> 12, n = m0 & 4095;

#pragma unroll
    for (int tile = 0; tile < 5; tile++) {
        bool isfg = (grp == 0) && (tile < 2);
        int n0 = (grp == 0) ? (isfg ? tile * 64 : (tile - 2) * 64)
                            : (tile + 3) * 64;
        const unsigned short* wt = isfg ? (wfg + (size_t)tile * 64 * 512)
                                        : (wth + (size_t)n0 * 512);

        f32x4 acc[4] = {f32x4{0,0,0,0}, f32x4{0,0,0,0}, f32x4{0,0,0,0}, f32x4{0,0,0,0}};
#pragma unroll 4
        for (int k0 = 0; k0 < 16; k0++)
#pragma unroll
            for (int cf = 0; cf < 4; cf++) {
                bf16x8 bb = ld8(wt + (size_t)(16 * cf + i) * 512 + 32 * k0 + g * 8);
                acc[cf] = mfma16(af[k0], bb, acc[cf]);
            }

        if (isfg) {
#pragma unroll
            for (int cf = 0; cf < 4; cf++)
#pragma unroll
                for (int r = 0; r < 4; r++)
                    fgb[(size_t)(m0 + 16 * w + 4 * g + r) * 128 + tile * 64 + 16 * cf + i] =
                        f2bf(acc[cf][r]);
        } else {
            __syncthreads();   // prior tile's Tl reads complete
#pragma unroll
            for (int cf = 0; cf < 4; cf++) {
                ushort4 v4;
                v4.x = f2bf(acc[cf][0]); v4.y = f2bf(acc[cf][1]);
                v4.z = f2bf(acc[cf][2]); v4.w = f2bf(acc[cf][3]);
                *reinterpret_cast<ushort4*>(&Tl[16 * cf + i][16 * w + 4 * g]) = v4;
            }
            __syncthreads();
            // sigma store: quartet wq of each 32-block -> slot (wq&3)*2+(wq>>2)
#pragma unroll
            for (int ch = tid; ch < 1024; ch += 256) {
                int row = ch >> 4, nq = ch & 15;
                int w32 = nq >> 3, wq = nq & 7;
                int pos = w32 * 32 + (((wq & 3) << 1) + (wq >> 2)) * 4;
                ushort4 d = *reinterpret_cast<const ushort4*>(&Tl[row][nq * 4]);
                *reinterpret_cast<ushort4*>(vt + ((size_t)(b * 512 + n0 + row)) * 4096 + n + pos) = d;
            }
        }
    }
}

// --------------------------- flash attention -------------------------------
// Grid 512 = 4 batch x 32 qtiles(128 rows) x 4 c-slices(128 cols).
// Block 256 thr / 4 waves; K/V double-buffered in LDS via global_load_lds.
// P stays in registers (sigma-matched k-order); l accumulated by ones-column
// MFMA (no VALU adds, no epilogue shuffles).
__global__ __launch_bounds__(256, 2) void attn_k(const unsigned short* __restrict__ fg,
                                                 const unsigned short* __restrict__ vt,
                                                 const float* __restrict__ x,
                                                 const float* __restrict__ gamma,
                                                 float* __restrict__ out) {
    __shared__ __align__(16) unsigned char Kl[2][8192];    // [64 j][128 B], XOR-swz
    __shared__ __align__(16) unsigned char Vl[2][16384];   // [128 c][128 B], XOR-swz

    int bid = blockIdx.x;
    int cs = bid & 3;
    int batch = (bid >> 2) & 3;
    int q = bid >> 4;
    int c0w = cs * 128;

    int tid = threadIdx.x;
    int w = tid >> 6, l = tid & 63, g = l >> 4, i = l & 15;
    int swz = (i & 7) << 4;
    int qbase = q * 128 + 32 * w;

    const unsigned short* fgb = fg + (size_t)batch * 4096 * 128;
    const char* vtB = (const char*)(vt + (size_t)batch * 512 * 4096);

    // staging source addresses (inverse-swizzled; LDS dest linear per lane)
    int kcol = (16 * (l & 7)) ^ (16 * (l >> 3));
    const char* kbase = (const char*)fgb + 128 + kcol + (size_t)(16 * w + (l >> 3)) * 256;
    const char* vbase = vtB + (size_t)(c0w + 32 * w + (l >> 3)) * 8192 + kcol;

    int koff0 = (16 * g) ^ swz, koff1 = (64 + 16 * g) ^ swz;

    // Q fragments, register-resident
    bf16x8 aQ[2][2];
#pragma unroll
    for (int qf = 0; qf < 2; qf++)
#pragma unroll
        for (int ks = 0; ks < 2; ks++)
            aQ[qf][ks] = ld8(fgb + (size_t)(qbase + 16 * qf + i) * 128 + ks * 32 + g * 8);

    // ones B-fragment for l = P . 1
    bf16x8 ones8;
#pragma unroll
    for (int z = 0; z < 8; z++) ones8[z] = (__bf16)1.0f;

    f32x4 acc[2][8];
#pragma unroll
    for (int a = 0; a < 2; a++)
#pragma unroll
        for (int b = 0; b < 8; b++) acc[a][b] = f32x4{0, 0, 0, 0};
    f32x4 lacc[2] = {f32x4{0,0,0,0}, f32x4{0,0,0,0}};

    // prologue: stage tile 0 into buf 0
    {
        unsigned char* Kd = &Kl[0][w * 2048];
        gl2lds16(kbase, Kd);
        gl2lds16(kbase + 2048, Kd + 1024);
        unsigned char* Vd = &Vl[0][w * 4096];
        gl2lds16(vbase, Vd);
        gl2lds16(vbase + 65536, Vd + 1024);
        gl2lds16(vbase + 131072, Vd + 2048);
        gl2lds16(vbase + 196608, Vd + 3072);
    }

    int p = 0;
    for (int t = 0; t < 64; ++t) {
        __syncthreads();   // vmcnt(0): stage(t) landed; all waves done with buf p^1

        if (t + 1 < 64) {  // stage tile t+1 into buf p^1
            size_t j0n = (size_t)(t + 1) * 64;
            unsigned char* Kd = &Kl[p ^ 1][w * 2048];
            const char* gk = kbase + j0n * 256;
            gl2lds16(gk, Kd);
            gl2lds16(gk + 2048, Kd + 1024);
            unsigned char* Vd = &Vl[p ^ 1][w * 4096];
            const char* gv = vbase + j0n * 2;
            gl2lds16(gv, Vd);
            gl2lds16(gv + 65536, Vd + 1024);
            gl2lds16(gv + 131072, Vd + 2048);
            gl2lds16(gv + 196608, Vd + 3072);
        }

        // ---- S^T = K Q^T : lane holds S[q=16qf+i][j=16jf+4g+r] ----
        const unsigned char* Kb = Kl[p];
        f32x4 sacc[4][2];
#pragma unroll
        for (int jf = 0; jf < 4; jf++)
#pragma unroll
            for (int qf = 0; qf < 2; qf++) sacc[jf][qf] = f32x4{0, 0, 0, 0};
        __builtin_amdgcn_s_setprio(1);
#pragma unroll
        for (int jf = 0; jf < 4; jf++) {
            const unsigned char* ra = Kb + (16 * jf + i) * 128;
            bf16x8 k0 = ld8(ra + koff0);
            bf16x8 k1 = ld8(ra + koff1);
            sacc[jf][0] = mfma16(k0, aQ[0][0], sacc[jf][0]);
            sacc[jf][1] = mfma16(k0, aQ[1][0], sacc[jf][1]);
            sacc[jf][0] = mfma16(k1, aQ[0][1], sacc[jf][0]);
            sacc[jf][1] = mfma16(k1, aQ[1][1], sacc[jf][1]);
        }
        __builtin_amdgcn_s_setprio(0);

        // ---- P = exp(S) (bounded; no max pass), pack to A-frags in regs ----
        bf16x8 aP[2][2];
#pragma unroll
        for (int qf = 0; qf < 2; qf++) {
            u32 pk[4][2];
#pragma unroll
            for (int jf = 0; jf < 4; jf++) {
                float p0 = __builtin_amdgcn_exp2f(sacc[jf][qf][0] * L2E);
                float p1 = __builtin_amdgcn_exp2f(sacc[jf][qf][1] * L2E);
                float p2 = __builtin_amdgcn_exp2f(sacc[jf][qf][2] * L2E);
                float p3 = __builtin_amdgcn_exp2f(sacc[jf][qf][3] * L2E);
                pk[jf][0] = cvtpk(p0, p1);
                pk[jf][1] = cvtpk(p2, p3);
            }
            aP[qf][0] = __builtin_bit_cast(bf16x8, u32x4{pk[0][0], pk[0][1], pk[1][0], pk[1][1]});
            aP[qf][1] = __builtin_bit_cast(bf16x8, u32x4{pk[2][0], pk[2][1], pk[3][0], pk[3][1]});
        }

        // ---- O += P @ V ; l += P @ 1 ----
        const unsigned char* Vb = Vl[p];
        __builtin_amdgcn_s_setprio(1);
#pragma unroll
        for (int cf = 0; cf < 8; cf++) {
            const unsigned char* rv = Vb + (16 * cf + i) * 128;
            bf16x8 v0 = ld8(rv + koff0);
            bf16x8 v1 = ld8(rv + koff1);
            acc[0][cf] = mfma16(aP[0][0], v0, acc[0][cf]);
            acc[0][cf] = mfma16(aP[0][1], v1, acc[0][cf]);
            acc[1][cf] = mfma16(aP[1][0], v0, acc[1][cf]);
            acc[1][cf] = mfma16(aP[1][1], v1, acc[1][cf]);
        }
        lacc[0] = mfma16(aP[0][0], ones8, lacc[0]);
        lacc[0] = mfma16(aP[0][1], ones8, lacc[0]);
        lacc[1] = mfma16(aP[1][0], ones8, lacc[1]);
        lacc[1] = mfma16(aP[1][1], ones8, lacc[1]);
        __builtin_amdgcn_s_setprio(0);
        p ^= 1;
    }

    // ---- epilogue: out = gamma*O/l + x (l already per-lane in lacc) ----
    float gam = gamma[0];
#pragma unroll
    for (int qf = 0; qf < 2; qf++) {
#pragma unroll
        for (int r = 0; r < 4; r++) {
            float linv = gam / lacc[qf][r];
            int n = qbase + 16 * qf + 4 * g + r;
            size_t base = ((size_t)batch * 4096 + n) * 512 + c0w;
#pragma unroll
            for (int cf = 0; cf < 8; cf++)
                out[base + 16 * cf + i] = acc[qf][cf][r] * linv + x[base + 16 * cf + i];
        }
    }
}

// --------------------------- launcher --------------------------------------

extern "C" void kernel_launch(void* const* d_in, const int* in_sizes, int n_in,
                              void* d_out, int out_size, void* d_ws, size_t ws_size,
                              hipStream_t stream) {
    const float* x = (const float*)d_in[0];
    const float* kf = (const float*)d_in[1];
    const float* kg = (const float*)d_in[2];
    const float* kh = (const float*)d_in[3];
    const float* gamma = (const float*)d_in[4];
    float* out = (float*)d_out;

    char* ws = (char*)d_ws;
    unsigned short* FGb = (unsigned short*)(ws);               // 4 MB
    unsigned short* Vt  = (unsigned short*)(ws + 4194304);     // 16 MB
    unsigned short* Wfg = (unsigned short*)(ws + 20971520);    // 128 KB
    unsigned short* Wth = (unsigned short*)(ws + 21102592);    // 512 KB

    cvt_w_all<<<1280, 256, 0, stream>>>(kf, kg, kh, Wfg, Wth);
    proj_k<<<dim3(256, 2), 256, 0, stream>>>(x, Wfg, Wth, FGb, Vt);
    attn_k<<<512, 256, 0, stream>>>(FGb, Vt, x, gamma, out);
}

// Round 7
// 196.447 us; speedup vs baseline: 1.0950x; 1.0950x over previous
//
#include <hip/hip_runtime.h>

// ---------------------------------------------------------------------------
// SelfAttention: B=4, N=4096 tokens/batch, C=512, DQK=64
// out = gamma * softmax((X Wf)(X Wg)^T) (X Wh) + X
// Round 7: fix proj_k scratch spill (full unroll -> af[] compile-time indexed,
// rule #20), fold log2(e) into Wf so attention softmax needs no multiply.
// ---------------------------------------------------------------------------

typedef __bf16 bf16x8 __attribute__((ext_vector_type(8)));
typedef __bf16 bf16x2 __attribute__((ext_vector_type(2)));
typedef float f32x4 __attribute__((ext_vector_type(4)));
typedef unsigned int u32x4 __attribute__((ext_vector_type(4)));
typedef unsigned int u32;

#define L2E 1.4426950408889634f

__device__ __forceinline__ unsigned short f2bf(float f) {
    unsigned int u = __builtin_bit_cast(unsigned int, f);
    u += 0x7fffu + ((u >> 16) & 1u);   // RNE
    return (unsigned short)(u >> 16);
}
__device__ __forceinline__ u32 cvtpk(float a, float b) {
    bf16x2 t; t[0] = (__bf16)a; t[1] = (__bf16)b;   // -> v_cvt_pk_bf16_f32
    return __builtin_bit_cast(u32, t);
}
__device__ __forceinline__ bf16x8 ld8(const void* p) {
    u32x4 u = *reinterpret_cast<const u32x4*>(p);
    return __builtin_bit_cast(bf16x8, u);
}
// two float4 loads + cvt_pk -> bf16x8 fragment
__device__ __forceinline__ bf16x8 ldx(const float* p) {
    float4 a = *reinterpret_cast<const float4*>(p);
    float4 b = *reinterpret_cast<const float4*>(p + 4);
    u32x4 r;
    r.x = cvtpk(a.x, a.y); r.y = cvtpk(a.z, a.w);
    r.z = cvtpk(b.x, b.y); r.w = cvtpk(b.z, b.w);
    return __builtin_bit_cast(bf16x8, r);
}
__device__ __forceinline__ f32x4 mfma16(bf16x8 a, bf16x8 b, f32x4 c) {
    return __builtin_amdgcn_mfma_f32_16x16x32_bf16(a, b, c, 0, 0, 0);
}
__device__ __forceinline__ void gl2lds16(const void* g, void* l) {
    __builtin_amdgcn_global_load_lds(
        (const __attribute__((address_space(1))) u32*)g,
        (__attribute__((address_space(3))) u32*)l, 16, 0, 0);
}

// --------------------------- prep kernel -----------------------------------

// all three weights -> transposed bf16, one launch; Wf pre-scaled by log2(e)
// so QK^T lands directly in the exp2 domain.
__global__ __launch_bounds__(256) void cvt_w_all(const float* __restrict__ kf,
                                                 const float* __restrict__ kg,
                                                 const float* __restrict__ kh,
                                                 unsigned short* __restrict__ wfg,
                                                 unsigned short* __restrict__ wth) {
    int idx = blockIdx.x * 256 + threadIdx.x;
    if (idx < 32768) {
        int n = idx >> 9, k = idx & 511;
        wfg[idx] = f2bf(kf[k * 64 + n] * L2E);
    } else if (idx < 65536) {
        int t = idx - 32768;
        int n = t >> 9, k = t & 511;
        wfg[idx] = f2bf(kg[k * 64 + n]);
    } else {
        int t = idx - 65536;
        int n = t >> 9, k = t & 511;
        wth[t] = f2bf(kh[k * 512 + n]);
    }
}

// --------------------- fused projection kernel -----------------------------
// Grid dim3(256, 2): [64-row m-stripe, column-group]. x read once per block
// into 16 bf16x8 register fragments (FULL unroll everywhere: af[] must be
// compile-time indexed or it spills to scratch); 5 output tiles per group.
//   group 0: FG tiles {0,1} -> FGb; V tiles n0 = {0,64,128}
//   group 1: V tiles n0 = {192,256,320,384,448}
// V tiles stored transposed (Vt[b][c][n]) with quartet sigma-interleave.
__global__ __launch_bounds__(256, 2) void proj_k(const float* __restrict__ x,
                                                 const unsigned short* __restrict__ wfg,
                                                 const unsigned short* __restrict__ wth,
                                                 unsigned short* __restrict__ fgb,
                                                 unsigned short* __restrict__ vt) {
    __shared__ unsigned short Tl[64][72];
    int m0 = blockIdx.x * 64;
    int grp = blockIdx.y;
    int tid = threadIdx.x;
    int w = tid >> 6, l = tid & 63, g = l >> 4, i = l & 15;

    const float* xrow = x + (size_t)(m0 + 16 * w + i) * 512 + g * 8;
    bf16x8 af[16];
#pragma unroll
    for (int k = 0; k < 16; k++) af[k] = ldx(xrow + 32 * k);

    int b = m0 >> 12, n = m0 & 4095;

#pragma unroll
    for (int tile = 0; tile < 5; tile++) {
        bool isfg = (grp == 0) && (tile < 2);
        int n0 = (grp == 0) ? (isfg ? tile * 64 : (tile - 2) * 64)
                            : (tile + 3) * 64;
        const unsigned short* wt = isfg ? (wfg + (size_t)tile * 64 * 512)
                                        : (wth + (size_t)n0 * 512);

        f32x4 acc[4] = {f32x4{0,0,0,0}, f32x4{0,0,0,0}, f32x4{0,0,0,0}, f32x4{0,0,0,0}};
#pragma unroll
        for (int k0 = 0; k0 < 16; k0++)
#pragma unroll
            for (int cf = 0; cf < 4; cf++) {
                bf16x8 bb = ld8(wt + (size_t)(16 * cf + i) * 512 + 32 * k0 + g * 8);
                acc[cf] = mfma16(af[k0], bb, acc[cf]);
            }

        if (isfg) {
#pragma unroll
            for (int cf = 0; cf < 4; cf++)
#pragma unroll
                for (int r = 0; r < 4; r++)
                    fgb[(size_t)(m0 + 16 * w + 4 * g + r) * 128 + tile * 64 + 16 * cf + i] =
                        f2bf(acc[cf][r]);
        } else {
            __syncthreads();   // prior tile's Tl reads complete
#pragma unroll
            for (int cf = 0; cf < 4; cf++) {
                ushort4 v4;
                v4.x = f2bf(acc[cf][0]); v4.y = f2bf(acc[cf][1]);
                v4.z = f2bf(acc[cf][2]); v4.w = f2bf(acc[cf][3]);
                *reinterpret_cast<ushort4*>(&Tl[16 * cf + i][16 * w + 4 * g]) = v4;
            }
            __syncthreads();
            // sigma store: quartet wq of each 32-block -> slot (wq&3)*2+(wq>>2)
#pragma unroll
            for (int ch = tid; ch < 1024; ch += 256) {
                int row = ch >> 4, nq = ch & 15;
                int w32 = nq >> 3, wq = nq & 7;
                int pos = w32 * 32 + (((wq & 3) << 1) + (wq >> 2)) * 4;
                ushort4 d = *reinterpret_cast<const ushort4*>(&Tl[row][nq * 4]);
                *reinterpret_cast<ushort4*>(vt + ((size_t)(b * 512 + n0 + row)) * 4096 + n + pos) = d;
            }
        }
    }
}

// --------------------------- flash attention -------------------------------
// Grid 512 = 4 batch x 32 qtiles(128 rows) x 4 c-slices(128 cols).
// Block 256 thr / 4 waves; K/V double-buffered in LDS via global_load_lds.
// P stays in registers (sigma-matched k-order); l accumulated by ones-column
// MFMA. S arrives pre-scaled by log2(e) (folded into Wf) -> exp2 directly.
__global__ __launch_bounds__(256, 2) void attn_k(const unsigned short* __restrict__ fg,
                                                 const unsigned short* __restrict__ vt,
                                                 const float* __restrict__ x,
                                                 const float* __restrict__ gamma,
                                                 float* __restrict__ out) {
    __shared__ __align__(16) unsigned char Kl[2][8192];    // [64 j][128 B], XOR-swz
    __shared__ __align__(16) unsigned char Vl[2][16384];   // [128 c][128 B], XOR-swz

    int bid = blockIdx.x;
    int cs = bid & 3;
    int batch = (bid >> 2) & 3;
    int q = bid >> 4;
    int c0w = cs * 128;

    int tid = threadIdx.x;
    int w = tid >> 6, l = tid & 63, g = l >> 4, i = l & 15;
    int swz = (i & 7) << 4;
    int qbase = q * 128 + 32 * w;

    const unsigned short* fgb = fg + (size_t)batch * 4096 * 128;
    const char* vtB = (const char*)(vt + (size_t)batch * 512 * 4096);

    // staging source addresses (inverse-swizzled; LDS dest linear per lane)
    int kcol = (16 * (l & 7)) ^ (16 * (l >> 3));
    const char* kbase = (const char*)fgb + 128 + kcol + (size_t)(16 * w + (l >> 3)) * 256;
    const char* vbase = vtB + (size_t)(c0w + 32 * w + (l >> 3)) * 8192 + kcol;

    int koff0 = (16 * g) ^ swz, koff1 = (64 + 16 * g) ^ swz;

    // Q fragments, register-resident
    bf16x8 aQ[2][2];
#pragma unroll
    for (int qf = 0; qf < 2; qf++)
#pragma unroll
        for (int ks = 0; ks < 2; ks++)
            aQ[qf][ks] = ld8(fgb + (size_t)(qbase + 16 * qf + i) * 128 + ks * 32 + g * 8);

    // ones B-fragment for l = P . 1
    bf16x8 ones8;
#pragma unroll
    for (int z = 0; z < 8; z++) ones8[z] = (__bf16)1.0f;

    f32x4 acc[2][8];
#pragma unroll
    for (int a = 0; a < 2; a++)
#pragma unroll
        for (int b = 0; b < 8; b++) acc[a][b] = f32x4{0, 0, 0, 0};
    f32x4 lacc[2] = {f32x4{0,0,0,0}, f32x4{0,0,0,0}};

    // prologue: stage tile 0 into buf 0
    {
        unsigned char* Kd = &Kl[0][w * 2048];
        gl2lds16(kbase, Kd);
        gl2lds16(kbase + 2048, Kd + 1024);
        unsigned char* Vd = &Vl[0][w * 4096];
        gl2lds16(vbase, Vd);
        gl2lds16(vbase + 65536, Vd + 1024);
        gl2lds16(vbase + 131072, Vd + 2048);
        gl2lds16(vbase + 196608, Vd + 3072);
    }

    int p = 0;
    for (int t = 0; t < 64; ++t) {
        __syncthreads();   // vmcnt(0): stage(t) landed; all waves done with buf p^1

        if (t + 1 < 64) {  // stage tile t+1 into buf p^1
            size_t j0n = (size_t)(t + 1) * 64;
            unsigned char* Kd = &Kl[p ^ 1][w * 2048];
            const char* gk = kbase + j0n * 256;
            gl2lds16(gk, Kd);
            gl2lds16(gk + 2048, Kd + 1024);
            unsigned char* Vd = &Vl[p ^ 1][w * 4096];
            const char* gv = vbase + j0n * 2;
            gl2lds16(gv, Vd);
            gl2lds16(gv + 65536, Vd + 1024);
            gl2lds16(gv + 131072, Vd + 2048);
            gl2lds16(gv + 196608, Vd + 3072);
        }

        // ---- S^T(log2) = K Q^T : lane holds S[q=16qf+i][j=16jf+4g+r] ----
        const unsigned char* Kb = Kl[p];
        f32x4 sacc[4][2];
#pragma unroll
        for (int jf = 0; jf < 4; jf++)
#pragma unroll
            for (int qf = 0; qf < 2; qf++) sacc[jf][qf] = f32x4{0, 0, 0, 0};
        __builtin_amdgcn_s_setprio(1);
#pragma unroll
        for (int jf = 0; jf < 4; jf++) {
            const unsigned char* ra = Kb + (16 * jf + i) * 128;
            bf16x8 k0 = ld8(ra + koff0);
            bf16x8 k1 = ld8(ra + koff1);
            sacc[jf][0] = mfma16(k0, aQ[0][0], sacc[jf][0]);
            sacc[jf][1] = mfma16(k0, aQ[1][0], sacc[jf][1]);
            sacc[jf][0] = mfma16(k1, aQ[0][1], sacc[jf][0]);
            sacc[jf][1] = mfma16(k1, aQ[1][1], sacc[jf][1]);
        }
        __builtin_amdgcn_s_setprio(0);

        // ---- P = exp2(S) (bounded; no max pass), pack to A-frags in regs ----
        bf16x8 aP[2][2];
#pragma unroll
        for (int qf = 0; qf < 2; qf++) {
            u32 pk[4][2];
#pragma unroll
            for (int jf = 0; jf < 4; jf++) {
                float p0 = __builtin_amdgcn_exp2f(sacc[jf][qf][0]);
                float p1 = __builtin_amdgcn_exp2f(sacc[jf][qf][1]);
                float p2 = __builtin_amdgcn_exp2f(sacc[jf][qf][2]);
                float p3 = __builtin_amdgcn_exp2f(sacc[jf][qf][3]);
                pk[jf][0] = cvtpk(p0, p1);
                pk[jf][1] = cvtpk(p2, p3);
            }
            aP[qf][0] = __builtin_bit_cast(bf16x8, u32x4{pk[0][0], pk[0][1], pk[1][0], pk[1][1]});
            aP[qf][1] = __builtin_bit_cast(bf16x8, u32x4{pk[2][0], pk[2][1], pk[3][0], pk[3][1]});
        }

        // ---- O += P @ V ; l += P @ 1 ----
        const unsigned char* Vb = Vl[p];
        __builtin_amdgcn_s_setprio(1);
#pragma unroll
        for (int cf = 0; cf < 8; cf++) {
            const unsigned char* rv = Vb + (16 * cf + i) * 128;
            bf16x8 v0 = ld8(rv + koff0);
            bf16x8 v1 = ld8(rv + koff1);
            acc[0][cf] = mfma16(aP[0][0], v0, acc[0][cf]);
            acc[0][cf] = mfma16(aP[0][1], v1, acc[0][cf]);
            acc[1][cf] = mfma16(aP[1][0], v0, acc[1][cf]);
            acc[1][cf] = mfma16(aP[1][1], v1, acc[1][cf]);
        }
        lacc[0] = mfma16(aP[0][0], ones8, lacc[0]);
        lacc[0] = mfma16(aP[0][1], ones8, lacc[0]);
        lacc[1] = mfma16(aP[1][0], ones8, lacc[1]);
        lacc[1] = mfma16(aP[1][1], ones8, lacc[1]);
        __builtin_amdgcn_s_setprio(0);
        p ^= 1;
    }

    // ---- epilogue: out = gamma*O/l + x (l already per-lane in lacc) ----
    float gam = gamma[0];
#pragma unroll
    for (int qf = 0; qf < 2; qf++) {
#pragma unroll
        for (int r = 0; r < 4; r++) {
            float linv = gam / lacc[qf][r];
            int n = qbase + 16 * qf + 4 * g + r;
            size_t base = ((size_t)batch * 4096 + n) * 512 + c0w;
#pragma unroll
            for (int cf = 0; cf < 8; cf++)
                out[base + 16 * cf + i] = acc[qf][cf][r] * linv + x[base + 16 * cf + i];
        }
    }
}

// --------------------------- launcher --------------------------------------

extern "C" void kernel_launch(void* const* d_in, const int* in_sizes, int n_in,
                              void* d_out, int out_size, void* d_ws, size_t ws_size,
                              hipStream_t stream) {
    const float* x = (const float*)d_in[0];
    const float* kf = (const float*)d_in[1];
    const float* kg = (const float*)d_in[2];
    const float* kh = (const float*)d_in[3];
    const float* gamma = (const float*)d_in[4];
    float* out = (float*)d_out;

    char* ws = (char*)d_ws;
    unsigned short* FGb = (unsigned short*)(ws);               // 4 MB
    unsigned short* Vt  = (unsigned short*)(ws + 4194304);     // 16 MB
    unsigned short* Wfg = (unsigned short*)(ws + 20971520);    // 128 KB
    unsigned short* Wth = (unsigned short*)(ws + 21102592);    // 512 KB

    cvt_w_all<<<1280, 256, 0, stream>>>(kf, kg, kh, Wfg, Wth);
    proj_k<<<dim3(256, 2), 256, 0, stream>>>(x, Wfg, Wth, FGb, Vt);
    attn_k<<<512, 256, 0, stream>>>(FGb, Vt, x, gamma, out);
}

// Round 8
// 132.593 us; speedup vs baseline: 1.6223x; 1.4816x over previous
//
#include <hip/hip_runtime.h>

// ---------------------------------------------------------------------------
// SelfAttention: B=4, N=4096 tokens/batch, C=512, DQK=64
// out = gamma * softmax((X Wf)(X Wg)^T) (X Wh) + X
// Round 8: proj_k rebuilt on the attn-proven global_load_lds double-buffer
// (W pre-staged in lane-consumption order by cvt_w_all; async chunk pipeline;
// all 10 output tiles from one x read). attn_k unchanged.
// ---------------------------------------------------------------------------

typedef __bf16 bf16x8 __attribute__((ext_vector_type(8)));
typedef __bf16 bf16x2 __attribute__((ext_vector_type(2)));
typedef float f32x4 __attribute__((ext_vector_type(4)));
typedef unsigned int u32x4 __attribute__((ext_vector_type(4)));
typedef unsigned int u32;

#define L2E 1.4426950408889634f

__device__ __forceinline__ unsigned short f2bf(float f) {
    unsigned int u = __builtin_bit_cast(unsigned int, f);
    u += 0x7fffu + ((u >> 16) & 1u);   // RNE
    return (unsigned short)(u >> 16);
}
__device__ __forceinline__ u32 cvtpk(float a, float b) {
    bf16x2 t; t[0] = (__bf16)a; t[1] = (__bf16)b;   // -> v_cvt_pk_bf16_f32
    return __builtin_bit_cast(u32, t);
}
__device__ __forceinline__ bf16x8 ld8(const void* p) {
    u32x4 u = *reinterpret_cast<const u32x4*>(p);
    return __builtin_bit_cast(bf16x8, u);
}
// two float4 loads + cvt_pk -> bf16x8 fragment
__device__ __forceinline__ bf16x8 ldx(const float* p) {
    float4 a = *reinterpret_cast<const float4*>(p);
    float4 b = *reinterpret_cast<const float4*>(p + 4);
    u32x4 r;
    r.x = cvtpk(a.x, a.y); r.y = cvtpk(a.z, a.w);
    r.z = cvtpk(b.x, b.y); r.w = cvtpk(b.z, b.w);
    return __builtin_bit_cast(bf16x8, r);
}
__device__ __forceinline__ f32x4 mfma16(bf16x8 a, bf16x8 b, f32x4 c) {
    return __builtin_amdgcn_mfma_f32_16x16x32_bf16(a, b, c, 0, 0, 0);
}
__device__ __forceinline__ void gl2lds16(const void* g, void* l) {
    __builtin_amdgcn_global_load_lds(
        (const __attribute__((address_space(1))) u32*)g,
        (__attribute__((address_space(3))) u32*)l, 16, 0, 0);
}

// --------------------------- prep kernel -----------------------------------
// W -> staged layout [16 chunks q][4 slots s][640 cols c][8 bf16]:
//   element (q,s,c,j) = W^T[c][k=32q+8s+j];  c<64: f (x log2e), c<128: g,
//   c>=128: h col c-128. This is exactly the order proj_k's waves consume,
//   so global_load_lds staging is linear and LDS reads are 2-way-bank (free).
__global__ __launch_bounds__(256) void cvt_w_all(const float* __restrict__ kf,
                                                 const float* __restrict__ kg,
                                                 const float* __restrict__ kh,
                                                 unsigned short* __restrict__ wst) {
    int idx = blockIdx.x * 256 + threadIdx.x;   // 327680 total
    int j = idx & 7;
    int gi = idx >> 3;
    int c = gi % 640;
    int sq = gi / 640;
    int k = (sq >> 2) * 32 + (sq & 3) * 8 + j;
    float v;
    if (c < 64)       v = kf[k * 64 + c] * L2E;
    else if (c < 128) v = kg[k * 64 + (c - 64)];
    else              v = kh[k * 512 + (c - 128)];
    wst[idx] = f2bf(v);
}

// --------------------- fused projection kernel -----------------------------
// Grid dim3(256, 2): [64-row m-stripe, col-group]. Per block: x rows read once
// into 16 register fragments; W streamed through a 2x20KB LDS double-buffer
// via global_load_lds (async, register-free). 5 output tiles of 64 cols:
//   grp 0: staged cols 0-319  = FG{0,1} + H n0={0,64,128}
//   grp 1: staged cols 320-639 = H n0={192,256,320,384,448}
// V tiles stored transposed (Vt[b][c][n]) with quartet sigma-interleave.
__global__ __launch_bounds__(256, 2) void proj_k(const float* __restrict__ x,
                                                 const unsigned short* __restrict__ wst,
                                                 unsigned short* __restrict__ fgb,
                                                 unsigned short* __restrict__ vt) {
    __shared__ __align__(16) unsigned char Wl[2][20480];   // [4 slots][320 cols][16B]
    __shared__ unsigned short Tl[64][72];

    int m0 = blockIdx.x * 64;
    int grp = blockIdx.y;
    int tid = threadIdx.x;
    int w = tid >> 6, l = tid & 63, g = l >> 4, i = l & 15;

    // staging source: wave w covers slot s=w of each chunk, this grp's 320 cols
    const char* wsrc = (const char*)wst + (size_t)w * 10240 + (size_t)grp * 5120 + l * 16;

    // stage chunk 0 into buf 0 (before af loads: overlaps x HBM latency)
#pragma unroll
    for (int s5 = 0; s5 < 5; s5++)
        gl2lds16(wsrc + s5 * 1024, &Wl[0][w * 5120 + s5 * 1024]);

    // x rows -> 16 bf16 fragments (register-resident; af[q] static-indexed)
    const float* xrow = x + (size_t)(m0 + 16 * w + i) * 512 + g * 8;
    bf16x8 af[16];
#pragma unroll
    for (int k = 0; k < 16; k++) af[k] = ldx(xrow + 32 * k);

    f32x4 acc[5][4];
#pragma unroll
    for (int t = 0; t < 5; t++)
#pragma unroll
        for (int cf = 0; cf < 4; cf++) acc[t][cf] = f32x4{0, 0, 0, 0};

    int rdoff = g * 5120 + i * 16;   // per-lane LDS read base (2-way banks)

#pragma unroll
    for (int q = 0; q < 16; q++) {
        __syncthreads();   // vmcnt(0) drain: chunk q staged; prior reads done

        if (q < 15) {      // stage chunk q+1 into the other buffer
            const char* src = wsrc + (size_t)(q + 1) * 40960;
#pragma unroll
            for (int s5 = 0; s5 < 5; s5++)
                gl2lds16(src + s5 * 1024, &Wl[(q + 1) & 1][w * 5120 + s5 * 1024]);
        }

        const unsigned char* Wb = &Wl[q & 1][0];
        __builtin_amdgcn_s_setprio(1);
#pragma unroll
        for (int t = 0; t < 5; t++)
#pragma unroll
            for (int cf = 0; cf < 4; cf++) {
                bf16x8 bb = ld8(Wb + rdoff + (t * 64 + 16 * cf) * 16);
                acc[t][cf] = mfma16(af[q], bb, acc[t][cf]);
            }
        __builtin_amdgcn_s_setprio(0);
    }

    int b = m0 >> 12, n = m0 & 4095;

#pragma unroll
    for (int t = 0; t < 5; t++) {
        bool isfg = (grp == 0) && (t < 2);
        if (isfg) {
#pragma unroll
            for (int cf = 0; cf < 4; cf++)
#pragma unroll
                for (int r = 0; r < 4; r++)
                    fgb[(size_t)(m0 + 16 * w + 4 * g + r) * 128 + t * 64 + 16 * cf + i] =
                        f2bf(acc[t][cf][r]);
        } else {
            int n0 = (grp == 0) ? (t - 2) * 64 : 192 + t * 64;
            __syncthreads();   // prior Tl reads (or Wl reads) complete
#pragma unroll
            for (int cf = 0; cf < 4; cf++) {
                ushort4 v4;
                v4.x = f2bf(acc[t][cf][0]); v4.y = f2bf(acc[t][cf][1]);
                v4.z = f2bf(acc[t][cf][2]); v4.w = f2bf(acc[t][cf][3]);
                *reinterpret_cast<ushort4*>(&Tl[16 * cf + i][16 * w + 4 * g]) = v4;
            }
            __syncthreads();
            // sigma store: quartet wq of each 32-block -> slot (wq&3)*2+(wq>>2)
#pragma unroll
            for (int ch = tid; ch < 1024; ch += 256) {
                int row = ch >> 4, nq = ch & 15;
                int w32 = nq >> 3, wq = nq & 7;
                int pos = w32 * 32 + (((wq & 3) << 1) + (wq >> 2)) * 4;
                ushort4 d = *reinterpret_cast<const ushort4*>(&Tl[row][nq * 4]);
                *reinterpret_cast<ushort4*>(vt + ((size_t)(b * 512 + n0 + row)) * 4096 + n + pos) = d;
            }
        }
    }
}

// --------------------------- flash attention -------------------------------
// Grid 512 = 4 batch x 32 qtiles(128 rows) x 4 c-slices(128 cols).
// Block 256 thr / 4 waves; K/V double-buffered in LDS via global_load_lds.
// P stays in registers (sigma-matched k-order); l accumulated by ones-column
// MFMA. S arrives pre-scaled by log2(e) (folded into Wf) -> exp2 directly.
__global__ __launch_bounds__(256, 2) void attn_k(const unsigned short* __restrict__ fg,
                                                 const unsigned short* __restrict__ vt,
                                                 const float* __restrict__ x,
                                                 const float* __restrict__ gamma,
                                                 float* __restrict__ out) {
    __shared__ __align__(16) unsigned char Kl[2][8192];    // [64 j][128 B], XOR-swz
    __shared__ __align__(16) unsigned char Vl[2][16384];   // [128 c][128 B], XOR-swz

    int bid = blockIdx.x;
    int cs = bid & 3;
    int batch = (bid >> 2) & 3;
    int q = bid >> 4;
    int c0w = cs * 128;

    int tid = threadIdx.x;
    int w = tid >> 6, l = tid & 63, g = l >> 4, i = l & 15;
    int swz = (i & 7) << 4;
    int qbase = q * 128 + 32 * w;

    const unsigned short* fgb = fg + (size_t)batch * 4096 * 128;
    const char* vtB = (const char*)(vt + (size_t)batch * 512 * 4096);

    // staging source addresses (inverse-swizzled; LDS dest linear per lane)
    int kcol = (16 * (l & 7)) ^ (16 * (l >> 3));
    const char* kbase = (const char*)fgb + 128 + kcol + (size_t)(16 * w + (l >> 3)) * 256;
    const char* vbase = vtB + (size_t)(c0w + 32 * w + (l >> 3)) * 8192 + kcol;

    int koff0 = (16 * g) ^ swz, koff1 = (64 + 16 * g) ^ swz;

    // Q fragments, register-resident
    bf16x8 aQ[2][2];
#pragma unroll
    for (int qf = 0; qf < 2; qf++)
#pragma unroll
        for (int ks = 0; ks < 2; ks++)
            aQ[qf][ks] = ld8(fgb + (size_t)(qbase + 16 * qf + i) * 128 + ks * 32 + g * 8);

    // ones B-fragment for l = P . 1
    bf16x8 ones8;
#pragma unroll
    for (int z = 0; z < 8; z++) ones8[z] = (__bf16)1.0f;

    f32x4 acc[2][8];
#pragma unroll
    for (int a = 0; a < 2; a++)
#pragma unroll
        for (int b = 0; b < 8; b++) acc[a][b] = f32x4{0, 0, 0, 0};
    f32x4 lacc[2] = {f32x4{0,0,0,0}, f32x4{0,0,0,0}};

    // prologue: stage tile 0 into buf 0
    {
        unsigned char* Kd = &Kl[0][w * 2048];
        gl2lds16(kbase, Kd);
        gl2lds16(kbase + 2048, Kd + 1024);
        unsigned char* Vd = &Vl[0][w * 4096];
        gl2lds16(vbase, Vd);
        gl2lds16(vbase + 65536, Vd + 1024);
        gl2lds16(vbase + 131072, Vd + 2048);
        gl2lds16(vbase + 196608, Vd + 3072);
    }

    int p = 0;
    for (int t = 0; t < 64; ++t) {
        __syncthreads();   // vmcnt(0): stage(t) landed; all waves done with buf p^1

        if (t + 1 < 64) {  // stage tile t+1 into buf p^1
            size_t j0n = (size_t)(t + 1) * 64;
            unsigned char* Kd = &Kl[p ^ 1][w * 2048];
            const char* gk = kbase + j0n * 256;
            gl2lds16(gk, Kd);
            gl2lds16(gk + 2048, Kd + 1024);
            unsigned char* Vd = &Vl[p ^ 1][w * 4096];
            const char* gv = vbase + j0n * 2;
            gl2lds16(gv, Vd);
            gl2lds16(gv + 65536, Vd + 1024);
            gl2lds16(gv + 131072, Vd + 2048);
            gl2lds16(gv + 196608, Vd + 3072);
        }

        // ---- S^T(log2) = K Q^T : lane holds S[q=16qf+i][j=16jf+4g+r] ----
        const unsigned char* Kb = Kl[p];
        f32x4 sacc[4][2];
#pragma unroll
        for (int jf = 0; jf < 4; jf++)
#pragma unroll
            for (int qf = 0; qf < 2; qf++) sacc[jf][qf] = f32x4{0, 0, 0, 0};
        __builtin_amdgcn_s_setprio(1);
#pragma unroll
        for (int jf = 0; jf < 4; jf++) {
            const unsigned char* ra = Kb + (16 * jf + i) * 128;
            bf16x8 k0 = ld8(ra + koff0);
            bf16x8 k1 = ld8(ra + koff1);
            sacc[jf][0] = mfma16(k0, aQ[0][0], sacc[jf][0]);
            sacc[jf][1] = mfma16(k0, aQ[1][0], sacc[jf][1]);
            sacc[jf][0] = mfma16(k1, aQ[0][1], sacc[jf][0]);
            sacc[jf][1] = mfma16(k1, aQ[1][1], sacc[jf][1]);
        }
        __builtin_amdgcn_s_setprio(0);

        // ---- P = exp2(S) (bounded; no max pass), pack to A-frags in regs ----
        bf16x8 aP[2][2];
#pragma unroll
        for (int qf = 0; qf < 2; qf++) {
            u32 pk[4][2];
#pragma unroll
            for (int jf = 0; jf < 4; jf++) {
                float p0 = __builtin_amdgcn_exp2f(sacc[jf][qf][0]);
                float p1 = __builtin_amdgcn_exp2f(sacc[jf][qf][1]);
                float p2 = __builtin_amdgcn_exp2f(sacc[jf][qf][2]);
                float p3 = __builtin_amdgcn_exp2f(sacc[jf][qf][3]);
                pk[jf][0] = cvtpk(p0, p1);
                pk[jf][1] = cvtpk(p2, p3);
            }
            aP[qf][0] = __builtin_bit_cast(bf16x8, u32x4{pk[0][0], pk[0][1], pk[1][0], pk[1][1]});
            aP[qf][1] = __builtin_bit_cast(bf16x8, u32x4{pk[2][0], pk[2][1], pk[3][0], pk[3][1]});
        }

        // ---- O += P @ V ; l += P @ 1 ----
        const unsigned char* Vb = Vl[p];
        __builtin_amdgcn_s_setprio(1);
#pragma unroll
        for (int cf = 0; cf < 8; cf++) {
            const unsigned char* rv = Vb + (16 * cf + i) * 128;
            bf16x8 v0 = ld8(rv + koff0);
            bf16x8 v1 = ld8(rv + koff1);
            acc[0][cf] = mfma16(aP[0][0], v0, acc[0][cf]);
            acc[0][cf] = mfma16(aP[0][1], v1, acc[0][cf]);
            acc[1][cf] = mfma16(aP[1][0], v0, acc[1][cf]);
            acc[1][cf] = mfma16(aP[1][1], v1, acc[1][cf]);
        }
        lacc[0] = mfma16(aP[0][0], ones8, lacc[0]);
        lacc[0] = mfma16(aP[0][1], ones8, lacc[0]);
        lacc[1] = mfma16(aP[1][0], ones8, lacc[1]);
        lacc[1] = mfma16(aP[1][1], ones8, lacc[1]);
        __builtin_amdgcn_s_setprio(0);
        p ^= 1;
    }

    // ---- epilogue: out = gamma*O/l + x (l already per-lane in lacc) ----
    float gam = gamma[0];
#pragma unroll
    for (int qf = 0; qf < 2; qf++) {
#pragma unroll
        for (int r = 0; r < 4; r++) {
            float linv = gam / lacc[qf][r];
            int n = qbase + 16 * qf + 4 * g + r;
            size_t base = ((size_t)batch * 4096 + n) * 512 + c0w;
#pragma unroll
            for (int cf = 0; cf < 8; cf++)
                out[base + 16 * cf + i] = acc[qf][cf][r] * linv + x[base + 16 * cf + i];
        }
    }
}

// --------------------------- launcher --------------------------------------

extern "C" void kernel_launch(void* const* d_in, const int* in_sizes, int n_in,
                              void* d_out, int out_size, void* d_ws, size_t ws_size,
                              hipStream_t stream) {
    const float* x = (const float*)d_in[0];
    const float* kf = (const float*)d_in[1];
    const float* kg = (const float*)d_in[2];
    const float* kh = (const float*)d_in[3];
    const float* gamma = (const float*)d_in[4];
    float* out = (float*)d_out;

    char* ws = (char*)d_ws;
    unsigned short* FGb = (unsigned short*)(ws);               // 4 MB
    unsigned short* Vt  = (unsigned short*)(ws + 4194304);     // 16 MB
    unsigned short* Wst = (unsigned short*)(ws + 20971520);    // 640 KB

    cvt_w_all<<<1280, 256, 0, stream>>>(kf, kg, kh, Wst);
    proj_k<<<dim3(256, 2), 256, 0, stream>>>(x, Wst, FGb, Vt);
    attn_k<<<512, 256, 0, stream>>>(FGb, Vt, x, gamma, out);
}